// Round 6
// baseline (2906.955 us; speedup 1.0000x reference)
//
#include <hip/hip_runtime.h>

#define S_LEN 128
#define T_LEN 64
#define BSZ   64
#define EMBD  256
#define HID_  512
#define DHID_ 1024
#define VOC_  32000
#define HSTR  1024

typedef float  f4_t  __attribute__((ext_vector_type(4)));
typedef float  f32x4 __attribute__((ext_vector_type(4)));
typedef short  s16x8 __attribute__((ext_vector_type(8)));
typedef __bf16 bf16x8 __attribute__((ext_vector_type(8)));
typedef unsigned short u16x4 __attribute__((ext_vector_type(4)));
typedef int    i32x2 __attribute__((ext_vector_type(2)));

// ---------------- workspace layout ----------------
// float offsets:
#define WS_CS   0ull                       // 131,072 fl (2 layers x (B,HSTR) fp32 c-state)
#define WS_BAR  (WS_CS + 131072ull)        // 32,768 ints (4 regions x 8192)
#define WS_BF   (WS_BAR + 32768ull)
// ushort offsets within bf16 region:
#define U_X0B   0ull                        // 2,097,152
#define U_HE0   (U_X0B  + 2097152ull)       // 8,388,608
#define U_HE1   (U_HE0  + 8388608ull)       // 8,388,608
#define U_HD0   (U_HE1  + 8388608ull)       // 4,194,304
#define U_HD1   (U_HD0  + 4194304ull)       // 4,194,304
#define U_HSB   (U_HD1  + 4194304ull)       // 131,072
#define U_E0W   (U_HSB  + 131072ull)        // 1,048,576
#define U_E1W   (U_E0W  + 1048576ull)       // 4,194,304
#define U_D0W   (U_E1W  + 4194304ull)       // 1,048,576
#define U_D1W   (U_D0W  + 1048576ull)       // 4,194,304
#define U_XWA   (U_D1W  + 4194304ull)       // 16,777,216 (bf16 xw, (T,4H,B))
#define U_XWB   (U_XWA  + 16777216ull)      // 16,777,216
#define U_WOUT  (U_XWB  + 16777216ull)      // 32,768,000

__device__ __forceinline__ unsigned short f2bf(float x) {
    unsigned u = __builtin_bit_cast(unsigned, x);
    return (unsigned short)((u + 0x7fffu + ((u >> 16) & 1u)) >> 16);
}
__device__ __forceinline__ float bf2f(unsigned u) {
    return __builtin_bit_cast(float, u << 16);
}

// ---------------- coherent (LLC-scope) memory helpers ----------------
__device__ __forceinline__ f4_t sc_load4(const void* p) {
    f4_t v;
    asm volatile("global_load_dwordx4 %0, %1, off sc0 sc1" : "=v"(v) : "v"(p));
    return v;                               // NOT ready until a vmcnt wait
}
__device__ __forceinline__ int sc_load1(const int* p) {
    int v;
    asm volatile("global_load_dword %0, %1, off sc0 sc1\n\ts_waitcnt vmcnt(0)"
                 : "=v"(v) : "v"(p) : "memory");
    return v;
}
__device__ __forceinline__ void sc_store_int(int* p, int v) {
    asm volatile("global_store_dword %0, %1, off sc0 sc1" :: "v"(p), "v"(v) : "memory");
}
__device__ __forceinline__ void sc_store8(void* p, i32x2 v) {
    asm volatile("global_store_dwordx2 %0, %1, off sc0 sc1" :: "v"(p), "v"(v) : "memory");
}
__device__ __forceinline__ unsigned g_load_us(const unsigned short* p) {  // plain cached
    unsigned v;
    asm volatile("global_load_ushort %0, %1, off" : "=v"(v) : "v"(p));
    return v;                               // NOT ready until a vmcnt wait
}
__device__ __forceinline__ void wait_vm0() {
    asm volatile("s_waitcnt vmcnt(0)" ::: "memory");
}
__device__ __forceinline__ void wait_vm4() {
    asm volatile("s_waitcnt vmcnt(4)" ::: "memory");
}

__device__ __forceinline__ void gload_lds16(const void* g, void* l) {
    __builtin_amdgcn_global_load_lds(
        (const __attribute__((address_space(1))) void*)g,
        (__attribute__((address_space(3))) void*)l, 16, 0, 0);
}

__device__ __forceinline__ float sigmoidf_(float x) { return 1.f / (1.f + expf(-x)); }

// ---------------- fp32 -> bf16 conversion ----------------
__global__ __launch_bounds__(256) void f2b_kernel(
    const float* __restrict__ in, unsigned short* __restrict__ out, int n4)
{
    const int stride = gridDim.x * 256;
    for (int i = blockIdx.x * 256 + threadIdx.x; i < n4; i += stride) {
        const float4 v = reinterpret_cast<const float4*>(in)[i];
        u16x4 o = { f2bf(v.x), f2bf(v.y), f2bf(v.z), f2bf(v.w) };
        reinterpret_cast<u16x4*>(out)[i] = o;
    }
}

// ---------------- embedding gathers (emit bf16) ----------------
__global__ __launch_bounds__(64) void embed_src_kernel(
    const int* __restrict__ toks, const float* __restrict__ emb,
    unsigned short* __restrict__ out)
{
    const int i = blockIdx.x;
    const int tok = toks[i];
    const float4 v = reinterpret_cast<const float4*>(emb + (size_t)tok * EMBD)[threadIdx.x];
    u16x4 o = { f2bf(v.x), f2bf(v.y), f2bf(v.z), f2bf(v.w) };
    reinterpret_cast<u16x4*>(out + (size_t)i * EMBD)[threadIdx.x] = o;
}

__global__ __launch_bounds__(64) void embed_dec_kernel(
    const int* __restrict__ sent, const int* __restrict__ targ,
    const float* __restrict__ emb, unsigned short* __restrict__ out)
{
    const int i = blockIdx.x;
    const int t = i >> 6, b = i & 63;
    const int tok = (t == 0) ? sent[(S_LEN - 1) * BSZ + b] : targ[(t - 1) * BSZ + b];
    const float4 v = reinterpret_cast<const float4*>(emb + (size_t)tok * EMBD)[threadIdx.x];
    u16x4 o = { f2bf(v.x), f2bf(v.y), f2bf(v.z), f2bf(v.w) };
    reinterpret_cast<u16x4*>(out + (size_t)i * EMBD)[threadIdx.x] = o;
}

// ---------------- bf16 MFMA GEMM:  C = A[M,K] * B[N,K]^T + b1 (+ b2) ----------------
// tmode 0: C fp32 row-major (M,N). tmode 1: C bf16 as (M/64, N, 64) = (T,4H,B).
__global__ __launch_bounds__(256) void gemm_bf16_kernel(
    const unsigned short* __restrict__ A, const unsigned short* __restrict__ B,
    const float* __restrict__ b1, const float* __restrict__ b2,
    void* __restrict__ Cv, int M, int N, int K, int nTN, int tmode)
{
    __shared__ __align__(16) unsigned short As[128 * 64];
    __shared__ __align__(16) unsigned short Bs[128 * 64];

    const int tid  = threadIdx.x;
    const int lane = tid & 63;
    const int wv   = tid >> 6;
    const int wm   = wv >> 1, wn = wv & 1;

    const int nwg = gridDim.x;
    const int q = nwg >> 3, r = nwg & 7;
    const int xcd = blockIdx.x & 7, io = blockIdx.x >> 3;
    const int wg = (xcd < r ? xcd * (q + 1) : r * (q + 1) + (xcd - r) * q) + io;
    const int bm = (wg / nTN) * 128;
    const int bn = (wg % nTN) * 128;

    f32x4 acc[4][4];
#pragma unroll
    for (int i = 0; i < 4; ++i)
#pragma unroll
        for (int j = 0; j < 4; ++j) acc[i][j] = (f32x4)0.f;

    const int lin_base = wv * 1024 + lane * 16;

    for (int k0 = 0; k0 < K; k0 += 64) {
        __syncthreads();
#pragma unroll
        for (int qc = 0; qc < 4; ++qc) {
            const int lin = qc * 4096 + lin_base;
            const int row = lin >> 7;
            const int c   = (lin >> 4) & 7;
            const int sc  = c ^ (row & 7);
            const size_t gofs  = (size_t)(bm + row) * K + k0 + sc * 8;
            const size_t gofsB = (size_t)(bn + row) * K + k0 + sc * 8;
            char* ldst  = (char*)As + qc * 4096 + wv * 1024;
            char* ldstB = (char*)Bs + qc * 4096 + wv * 1024;
            gload_lds16(A + gofs, ldst);
            gload_lds16(B + gofsB, ldstB);
        }
        asm volatile("s_waitcnt vmcnt(0)" ::: "memory");
        __syncthreads();
#pragma unroll
        for (int ks = 0; ks < 2; ++ks) {
            bf16x8 af[4], bfv[4];
            const int ca = ks * 4 + (lane >> 4);
#pragma unroll
            for (int f = 0; f < 4; ++f) {
                const int ra = wm * 64 + f * 16 + (lane & 15);
                af[f] = __builtin_bit_cast(bf16x8,
                    *(const s16x8*)((const char*)As + ra * 128 + ((ca ^ (ra & 7)) << 4)));
                const int rb = wn * 64 + f * 16 + (lane & 15);
                bfv[f] = __builtin_bit_cast(bf16x8,
                    *(const s16x8*)((const char*)Bs + rb * 128 + ((ca ^ (rb & 7)) << 4)));
            }
#pragma unroll
            for (int i = 0; i < 4; ++i)
#pragma unroll
                for (int j = 0; j < 4; ++j)
                    acc[i][j] = __builtin_amdgcn_mfma_f32_16x16x32_bf16(
                        af[i], bfv[j], acc[i][j], 0, 0, 0);
        }
    }

    const int col0 = bn + wn * 64 + (lane & 15);
    if (tmode == 0) {
        float* C = (float*)Cv;
        const int row0 = bm + wm * 64 + ((lane >> 4) << 2);
#pragma unroll
        for (int i = 0; i < 4; ++i) {
#pragma unroll
            for (int j = 0; j < 4; ++j) {
                const int col = col0 + j * 16;
                float bias = b1[col];
                if (b2) bias += b2[col];
#pragma unroll
                for (int rg = 0; rg < 4; ++rg)
                    C[(size_t)(row0 + i * 16 + rg) * N + col] = acc[i][j][rg] + bias;
            }
        }
    } else {
        unsigned short* C = (unsigned short*)Cv;
        const int tblk = (bm >> 6) + wm;
        const int rb = (lane >> 4) << 2;
#pragma unroll
        for (int i = 0; i < 4; ++i) {
#pragma unroll
            for (int j = 0; j < 4; ++j) {
                const int col = col0 + j * 16;
                float bias = b1[col];
                if (b2) bias += b2[col];
                u16x4 o = { f2bf(acc[i][j][0] + bias), f2bf(acc[i][j][1] + bias),
                            f2bf(acc[i][j][2] + bias), f2bf(acc[i][j][3] + bias) };
                *reinterpret_cast<u16x4*>(&C[((size_t)tblk * N + col) * 64 + rb + i * 16]) = o;
            }
        }
    }
}

// ---------------- persistent MFMA LSTM scan, 512 threads, big gate-blocks ----------------
// enc: <512,16> grid 64 (2 dirs x 32 blocks, 64 gate-rows each).
// dec: <1024,8> grid 128 (32 gate-rows each).
// xw: bf16 (T, 4*H_T, B) per dir. hist: (T,B,1024) bf16 (h history AND y).
// Waves: 8 = 4 batch-quads x 2 gate-halves; Whh bf16 fragments in registers.
template<int H_T, int CELLS>
__global__ __launch_bounds__(512, 1) void lstm_mfma_scan(
    const unsigned short* __restrict__ xw0, const unsigned short* __restrict__ xw1,
    const float* __restrict__ Whh0, const float* __restrict__ Whh1,
    const unsigned short* __restrict__ h0b, const float* __restrict__ c0,
    unsigned short* __restrict__ hist,
    unsigned short* __restrict__ hsb, float* __restrict__ csd,
    int T, int ndir, int rev_mask, int* bar)
{
    constexpr int KST   = H_T / 32;           // MFMA k-steps
    constexpr int CH    = H_T / 8;            // 16B chunks per h row
    constexpr int NB    = (64 * CH) / 2048;   // staging batches (4 chunks/thread each)
    constexpr int NGQ   = CELLS / 8;          // gate-quads per wave
    constexpr int PAIRS = CELLS / 8;          // (b,cell) pairs per thread
    constexpr int CH8   = CELLS / 4;          // 8B h-store chunks per batch row

    __shared__ __align__(16) unsigned short h_lds[64 * H_T];   // 64/128 KB
    __shared__ float pre[4][CELLS][65];
    __shared__ __align__(8) unsigned short hpack[64][CELLS + 4];

    const int tid  = threadIdx.x;
    const int lane = tid & 63;
    const int w    = tid >> 6;
    const int bq   = w & 3;                  // batch quad
    const int gh   = w >> 2;                 // gate half
    const int n    = lane & 15;
    const int kg   = lane >> 4;
    const int bpd  = H_T / CELLS;            // blocks per dir
    const int dir  = blockIdx.x / bpd;
    const int blk  = blockIdx.x - dir * bpd;
    const int m0c  = blk * CELLS;            // cell base
    const int rev  = (rev_mask >> dir) & 1;
    const unsigned short* xw = dir ? xw1 : xw0;
    const float* Whh = dir ? Whh1 : Whh0;
    const int dcol = dir * H_T;

    int* myflag = bar + blockIdx.x * 32;
    const int* pollflag = bar + (dir * bpd + (tid < bpd ? tid : 0)) * 32;
    const bool polls = (tid < bpd);

    // ---- B-fragments: this wave's gate-rows in registers, bf16 ----
    s16x8 wfr[NGQ][KST];
#pragma unroll
    for (int qq = 0; qq < NGQ; ++qq) {
        int g, cc;
        if constexpr (CELLS == 16) { g = 2 * gh + qq; cc = n; }
        else                       { g = 2 * gh + (n >> 3); cc = n & 7; }
        const size_t wr = (size_t)(g * H_T + m0c + cc) * H_T;
#pragma unroll
        for (int ks = 0; ks < KST; ++ks) {
            const float* wp = Whh + wr + ks * 32 + kg * 8;
            const float4 lo = *reinterpret_cast<const float4*>(wp);
            const float4 hi = *reinterpret_cast<const float4*>(wp + 4);
            s16x8 rr;
            rr[0] = (short)f2bf(lo.x); rr[1] = (short)f2bf(lo.y);
            rr[2] = (short)f2bf(lo.z); rr[3] = (short)f2bf(lo.w);
            rr[4] = (short)f2bf(hi.x); rr[5] = (short)f2bf(hi.y);
            rr[6] = (short)f2bf(hi.z); rr[7] = (short)f2bf(hi.w);
            wfr[qq][ks] = rr;
        }
    }

    // ---- per-thread (b,cell) pairs, c-state, xw prefetch regs ----
    float cst[PAIRS];
    unsigned xg[PAIRS * 4];
#pragma unroll
    for (int i = 0; i < PAIRS; ++i) {
        const int p = tid + i * 512;
        const int b_ = p & 63, ci = p >> 6;
        cst[i] = c0 ? c0[(size_t)b_ * HSTR + dcol + m0c + ci] : 0.f;
    }

    auto issue_xg = [&](int ttn) {
#pragma unroll
        for (int i = 0; i < PAIRS; ++i) {
            const int p = tid + i * 512;
            const int b_ = p & 63, ci = p >> 6;
#pragma unroll
            for (int g = 0; g < 4; ++g)
                xg[i * 4 + g] = g_load_us(
                    xw + ((size_t)ttn * (4 * H_T) + g * H_T + m0c + ci) * 64 + b_);
        }
    };

    const int rA  = bq * 16 + n;             // A-frag LDS row (batch)
    const int rAx = rA & 7;
    float hnv[PAIRS];

    issue_xg(rev ? (T - 1) : 0);
    wait_vm0();                              // clean counters before staged loop

    for (int s = 0; s < T; ++s) {
        const int tt = rev ? (T - 1 - s) : s;

        // wait for all producers of step s-1 (single-hop; also drains xg prefetch)
        if (s > 0) {
            int ok = polls ? 0 : 1;
            for (;;) {
                if (!ok) ok = (sc_load1(pollflag) >= s) ? 1 : 0;
                if (__syncthreads_and(ok)) break;
            }
        }

        const unsigned short* hb;
        size_t tofs;
        if (s == 0) { hb = h0b; tofs = 0; }
        else {
            const int tp = rev ? (tt + 1) : (tt - 1);
            hb = hist; tofs = (size_t)tp * (64 * 1024);
        }

        float p_[4][PAIRS];
#pragma unroll
        for (int g = 0; g < 4; ++g)
#pragma unroll
            for (int i = 0; i < PAIRS; ++i) p_[g][i] = 0.f;

        if (hb) {
            // ---- stage h tile: sc_load4 -> XOR-swizzled LDS, 2-deep counted pipeline ----
            f4_t bufA[4], bufB[4];
            auto issue = [&](f4_t (&bf)[4], int bt) {
#pragma unroll
                for (int jj = 0; jj < 4; ++jj) {
                    const int idx = (bt * 4 + jj) * 512 + tid;
                    const int rr_ = idx / CH, cc_ = idx % CH;
                    bf[jj] = sc_load4(hb + tofs + (size_t)rr_ * 1024 + dcol + cc_ * 8);
                }
            };
            auto writeb = [&](const f4_t (&bf)[4], int bt) {
#pragma unroll
                for (int jj = 0; jj < 4; ++jj) {
                    const int idx = (bt * 4 + jj) * 512 + tid;
                    const int rr_ = idx / CH, cc_ = idx % CH;
                    const int off = rr_ * (2 * H_T) + ((cc_ ^ (rr_ & 7)) << 4);
                    *(f4_t*)((char*)h_lds + off) = bf[jj];
                }
            };
            issue(bufA, 0);
            if (NB > 1) issue(bufB, 1);
#pragma unroll
            for (int bt = 0; bt < NB; ++bt) {
                if (bt + 1 < NB) wait_vm4(); else wait_vm0();
                if (bt & 1) writeb(bufB, bt); else writeb(bufA, bt);
                if (bt + 2 < NB) { if (bt & 1) issue(bufB, bt + 2); else issue(bufA, bt + 2); }
            }
            __syncthreads();

            // ---- MFMA: one A-frag per k-step, reused across this wave's gate-quads ----
            f32x4 acc[NGQ];
#pragma unroll
            for (int qq = 0; qq < NGQ; ++qq) acc[qq] = (f32x4)0.f;
#pragma unroll
            for (int ks = 0; ks < KST; ++ks) {
                const int cc_ = ks * 4 + kg;
                const int off = rA * (2 * H_T) + ((cc_ ^ rAx) << 4);
                const bf16x8 a = __builtin_bit_cast(bf16x8,
                    *(const s16x8*)((const char*)h_lds + off));
#pragma unroll
                for (int qq = 0; qq < NGQ; ++qq)
                    acc[qq] = __builtin_amdgcn_mfma_f32_16x16x32_bf16(
                        a, __builtin_bit_cast(bf16x8, wfr[qq][ks]), acc[qq], 0, 0, 0);
            }
            // ---- exchange D -> pre[gate][cell][batch] ----
#pragma unroll
            for (int qq = 0; qq < NGQ; ++qq) {
                int g, cc;
                if constexpr (CELLS == 16) { g = 2 * gh + qq; cc = n; }
                else                       { g = 2 * gh + (n >> 3); cc = n & 7; }
#pragma unroll
                for (int rg = 0; rg < 4; ++rg)
                    pre[g][cc][bq * 16 + kg * 4 + rg] = acc[qq][rg];
            }
            __syncthreads();
#pragma unroll
            for (int i = 0; i < PAIRS; ++i) {
                const int p = tid + i * 512;
                const int b_ = p & 63, ci = p >> 6;
                p_[0][i] = pre[0][ci][b_]; p_[1][i] = pre[1][ci][b_];
                p_[2][i] = pre[2][ci][b_]; p_[3][i] = pre[3][ci][b_];
            }
        }

        // tie xw prefetch values to a vmcnt wait (they were issued last step)
        if constexpr (PAIRS == 2)
            asm volatile("s_waitcnt vmcnt(0)"
                : "+v"(xg[0]), "+v"(xg[1]), "+v"(xg[2]), "+v"(xg[3]),
                  "+v"(xg[4]), "+v"(xg[5]), "+v"(xg[6]), "+v"(xg[7]) :: "memory");
        else
            asm volatile("s_waitcnt vmcnt(0)"
                : "+v"(xg[0]), "+v"(xg[1]), "+v"(xg[2]), "+v"(xg[3]) :: "memory");

#pragma unroll
        for (int i = 0; i < PAIRS; ++i) {
            const int p = tid + i * 512;
            const int b_ = p & 63, ci = p >> 6;
            const float ig = sigmoidf_(p_[0][i] + bf2f(xg[i * 4 + 0]));
            const float fg = sigmoidf_(p_[1][i] + bf2f(xg[i * 4 + 1]));
            const float gg = tanhf   (p_[2][i] + bf2f(xg[i * 4 + 2]));
            const float og = sigmoidf_(p_[3][i] + bf2f(xg[i * 4 + 3]));
            cst[i] = fg * cst[i] + ig * gg;
            hnv[i] = og * tanhf(cst[i]);
            hpack[b_][ci] = f2bf(hnv[i]);
        }
        __syncthreads();
        if (tid < 64 * CH8) {
            const int b_ = tid / CH8, ch = tid - b_ * CH8;
            const i32x2 v2 = *reinterpret_cast<const i32x2*>(&hpack[b_][ch * 4]);
            sc_store8(hist + (size_t)tt * (64 * 1024) + (size_t)b_ * 1024 + dcol + m0c + ch * 4, v2);
        }
        wait_vm0();
        __syncthreads();                      // all stores drained before flag
        if (s + 1 < T) {
            if (tid == 0) sc_store_int(myflag, s + 1);
            issue_xg(rev ? (T - 2 - s) : (s + 1));   // prefetch next step's xw
        }
    }

    if (hsb) {
#pragma unroll
        for (int i = 0; i < PAIRS; ++i) {
            const int p = tid + i * 512;
            const int b_ = p & 63, ci = p >> 6;
            hsb[(size_t)b_ * 1024 + dcol + m0c + ci] = f2bf(hnv[i]);
            csd[(size_t)b_ * HSTR + dcol + m0c + ci] = cst[i];
        }
    }
}

// ---------------- in-place row log-softmax (float4) ----------------
__global__ __launch_bounds__(256) void logsoftmax_kernel(float* __restrict__ x, int n4)
{
    const int tid = threadIdx.x;
    float4* p = reinterpret_cast<float4*>(x + (size_t)blockIdx.x * (n4 * 4));
    float m = -3.0e38f, s = 0.f;
    for (int cc = tid; cc < n4; cc += 256) {
        const float4 v = p[cc];
        const float vv[4] = { v.x, v.y, v.z, v.w };
#pragma unroll
        for (int e = 0; e < 4; ++e) {
            const float z = vv[e];
            if (z > m) { s = s * expf(m - z) + 1.f; m = z; }
            else       { s += expf(z - m); }
        }
    }
    __shared__ float ms[256], ss[256];
    ms[tid] = m; ss[tid] = s;
    __syncthreads();
    for (int off = 128; off > 0; off >>= 1) {
        if (tid < off) {
            const float m2 = ms[tid + off], s2 = ss[tid + off];
            const float m1 = ms[tid],       s1 = ss[tid];
            const float M = fmaxf(m1, m2);
            ss[tid] = s1 * expf(m1 - M) + s2 * expf(m2 - M);
            ms[tid] = M;
        }
        __syncthreads();
    }
    const float ML = ms[0] + logf(ss[0]);
    for (int cc = tid; cc < n4; cc += 256) {
        float4 v = p[cc];
        v.x -= ML; v.y -= ML; v.z -= ML; v.w -= ML;
        p[cc] = v;
    }
}

// ---------------- host-side orchestration ----------------
extern "C" void kernel_launch(void* const* d_in, const int* in_sizes, int n_in,
                              void* d_out, int out_size, void* d_ws, size_t ws_size,
                              hipStream_t stream)
{
    const int*   sent  = (const int*)d_in[0];
    const int*   targ  = (const int*)d_in[1];
    const float* emb   = (const float*)d_in[2];
    const float* e0Wih = (const float*)d_in[3];
    const float* e0Whh = (const float*)d_in[4];
    const float* e0bih = (const float*)d_in[5];
    const float* e0bhh = (const float*)d_in[6];
    const float* e1Wih = (const float*)d_in[7];
    const float* e1Whh = (const float*)d_in[8];
    const float* e1bih = (const float*)d_in[9];
    const float* e1bhh = (const float*)d_in[10];
    const float* d0Wih = (const float*)d_in[11];
    const float* d0Whh = (const float*)d_in[12];
    const float* d0bih = (const float*)d_in[13];
    const float* d0bhh = (const float*)d_in[14];
    const float* d1Wih = (const float*)d_in[15];
    const float* d1Whh = (const float*)d_in[16];
    const float* d1bih = (const float*)d_in[17];
    const float* d1bhh = (const float*)d_in[18];
    const float* Wout  = (const float*)d_in[19];
    const float* bout  = (const float*)d_in[20];

    float* ws  = (float*)d_ws;
    float* cs  = ws + WS_CS;
    int*   bar = (int*)(ws + WS_BAR);
    unsigned short* ub    = (unsigned short*)(ws + WS_BF);
    unsigned short* x0b   = ub + U_X0B;
    unsigned short* h_e0  = ub + U_HE0;
    unsigned short* h_e1  = ub + U_HE1;
    unsigned short* h_d0  = ub + U_HD0;
    unsigned short* h_d1  = ub + U_HD1;
    unsigned short* hsb   = ub + U_HSB;
    unsigned short* e0Wb  = ub + U_E0W;
    unsigned short* e1Wb  = ub + U_E1W;
    unsigned short* d0Wb  = ub + U_D0W;
    unsigned short* d1Wb  = ub + U_D1W;
    unsigned short* xwA   = ub + U_XWA;
    unsigned short* xwB   = ub + U_XWB;
    unsigned short* Woutb = ub + U_WOUT;
    float* out = (float*)d_out;

    hipMemsetAsync(bar, 0, 4 * 8192 * sizeof(int), stream);

    // ---- weight conversions (fp32 -> bf16) ----
    f2b_kernel<<<256, 256, 0, stream>>>(e0Wih, e0Wb, 1048576 / 4);
    f2b_kernel<<<512, 256, 0, stream>>>(e1Wih, e1Wb, 4194304 / 4);
    f2b_kernel<<<256, 256, 0, stream>>>(d0Wih, d0Wb, 1048576 / 4);
    f2b_kernel<<<512, 256, 0, stream>>>(d1Wih, d1Wb, 4194304 / 4);
    f2b_kernel<<<2048, 256, 0, stream>>>(Wout, Woutb, (VOC_ * DHID_) / 4);

    // ---- encoder layer 0 ----
    embed_src_kernel<<<S_LEN * BSZ, 64, 0, stream>>>(sent, emb, x0b);
    gemm_bf16_kernel<<<64 * 16, 256, 0, stream>>>(x0b, e0Wb, e0bih, e0bhh, xwA,
                                                  S_LEN * BSZ, 2048, EMBD, 16, 1);
    gemm_bf16_kernel<<<64 * 16, 256, 0, stream>>>(x0b, e0Wb + 2048ull * 256,
                                                  e0bih + 2048, e0bhh + 2048, xwB,
                                                  S_LEN * BSZ, 2048, EMBD, 16, 1);
    lstm_mfma_scan<512, 16><<<64, 512, 0, stream>>>(xwA, xwB, e0Whh, e0Whh + 2048ull * 512,
                                                    nullptr, nullptr, h_e0,
                                                    hsb, cs, S_LEN, 2, 2, bar);
    // ---- encoder layer 1 (final states only) ----
    gemm_bf16_kernel<<<64 * 16, 256, 0, stream>>>(h_e0, e1Wb, e1bih, e1bhh, xwA,
                                                  S_LEN * BSZ, 2048, 2 * HID_, 16, 1);
    gemm_bf16_kernel<<<64 * 16, 256, 0, stream>>>(h_e0, e1Wb + 2048ull * 1024,
                                                  e1bih + 2048, e1bhh + 2048, xwB,
                                                  S_LEN * BSZ, 2048, 2 * HID_, 16, 1);
    lstm_mfma_scan<512, 16><<<64, 512, 0, stream>>>(xwA, xwB, e1Whh, e1Whh + 2048ull * 512,
                                                    nullptr, nullptr, h_e1,
                                                    hsb + 65536, cs + 65536,
                                                    S_LEN, 2, 2, bar + 8192);
    // ---- decoder layer 0 ----
    embed_dec_kernel<<<T_LEN * BSZ, 64, 0, stream>>>(sent, targ, emb, x0b);
    gemm_bf16_kernel<<<32 * 32, 256, 0, stream>>>(x0b, d0Wb, d0bih, d0bhh, xwA,
                                                  T_LEN * BSZ, 4 * DHID_, EMBD, 32, 1);
    lstm_mfma_scan<1024, 8><<<128, 512, 0, stream>>>(xwA, nullptr, d0Whh, nullptr,
                                                     hsb, cs, h_d0,
                                                     nullptr, nullptr, T_LEN, 1, 0,
                                                     bar + 2 * 8192);
    // ---- decoder layer 1 ----
    gemm_bf16_kernel<<<32 * 32, 256, 0, stream>>>(h_d0, d1Wb, d1bih, d1bhh, xwB,
                                                  T_LEN * BSZ, 4 * DHID_, DHID_, 32, 1);
    lstm_mfma_scan<1024, 8><<<128, 512, 0, stream>>>(xwB, nullptr, d1Whh, nullptr,
                                                     hsb + 65536, cs + 65536, h_d1,
                                                     nullptr, nullptr, T_LEN, 1, 0,
                                                     bar + 3 * 8192);
    // ---- vocab projection + log-softmax ----
    gemm_bf16_kernel<<<32 * 250, 256, 0, stream>>>(h_d1, Woutb, bout, nullptr, out,
                                                   T_LEN * BSZ, VOC_, DHID_, 250, 0);
    logsoftmax_kernel<<<T_LEN * BSZ, 256, 0, stream>>>(out, VOC_ / 4);
}